// Round 10
// baseline (127.337 us; speedup 1.0000x reference)
//
#include <hip/hip_runtime.h>

#define AS_GLOBAL __attribute__((address_space(1)))
#define AS_LDS    __attribute__((address_space(3)))

typedef __bf16 bf16;
typedef __bf16 bf16x4 __attribute__((ext_vector_type(4)));
typedef __bf16 bf16x8 __attribute__((ext_vector_type(8)));
typedef float  f32x4  __attribute__((ext_vector_type(4)));
typedef unsigned short u16x8 __attribute__((ext_vector_type(8)));

__device__ __forceinline__ void gload16(const void* g, void* l) {
  __builtin_amdgcn_global_load_lds((const AS_GLOBAL unsigned int*)g,
                                   (AS_LDS unsigned int*)l, 16, 0, 0);
}

// swizzled LDS address for a [R][128B] row-major tile:
// stored_byte = row*128 + (bytecol ^ ((row&7)<<4))
__device__ __forceinline__ void* swz(void* base, int row, int bytecol) {
  return (char*)base + row * 128 + (bytecol ^ ((row & 7) << 4));
}

// compacted-column helpers: kept columns are s with !(s%3==1 && s>=4).
__device__ __forceinline__ int keptcnt(int X) { return X - ((X - 2) < 0 ? 0 : (X - 2) / 3); }
__device__ __forceinline__ int ci2s(int ci) {
  return 3 * ((ci - 2) >> 1) + 2 + ((ci - 2) & 1);
}
__device__ __forceinline__ int ci2s_full(int ci) {
  return ci < 2 ? ci : ci2s(ci);
}

// ---------------- prep kernels ----------------

__global__ __launch_bounds__(256) void k_cvt_bf16(const float* __restrict__ x,
                                                  bf16* __restrict__ o, int n8) {
  int i = blockIdx.x * blockDim.x + threadIdx.x;
  if (i >= n8) return;
  const float4* p = (const float4*)(x + (size_t)i * 8);
  float4 a = p[0], b = p[1];
  bf16x8 v;
  v[0] = (bf16)a.x; v[1] = (bf16)a.y; v[2] = (bf16)a.z; v[3] = (bf16)a.w;
  v[4] = (bf16)b.x; v[5] = (bf16)b.y; v[6] = (bf16)b.z; v[7] = (bf16)b.w;
  *(bf16x8*)(o + (size_t)i * 8) = v;
}

// All four W transposes + bias concat in ONE launch (grid 2060).
// Blocks 0-511: Wq, 512-1023: Wk, 1024-1535: Wv, 1536-2047: Wp, 2048-2059: bcat.
__global__ __launch_bounds__(256) void k_wt_all(const float* __restrict__ Wq,
                                                const float* __restrict__ Wk,
                                                const float* __restrict__ Wv,
                                                const float* __restrict__ Wp,
                                                const float* __restrict__ bq,
                                                const float* __restrict__ bk,
                                                const float* __restrict__ bv,
                                                bf16* __restrict__ wqkvT,
                                                bf16* __restrict__ wpT,
                                                float* __restrict__ bc) {
  int blk = blockIdx.x;
  if (blk >= 2048) {
    int i = (blk - 2048) * 256 + threadIdx.x;   // 0..3071
    bc[i] = (i < 1024) ? bq[i] : (i < 2048 ? bk[i - 1024] : bv[i - 2048]);
    return;
  }
  int sel = blk >> 9;
  const float* W = (sel == 0) ? Wq : (sel == 1) ? Wk : (sel == 2) ? Wv : Wp;
  bf16* dst = (sel < 3) ? (wqkvT + (size_t)sel * 1024 * 1024) : wpT;
  int lin = (blk & 511) * 256 + threadIdx.x;
  int n = lin & 1023, kc = lin >> 10;
  bf16x8 v;
#pragma unroll
  for (int j = 0; j < 8; ++j) v[j] = (bf16)W[(size_t)(kc * 8 + j) * 1024 + n];
  *(bf16x8*)&dst[(size_t)n * 1024 + kc * 8] = v;
}

// gather compact x rows: xc[(b*1408+ci)][1024] = xb[(b*2048+s)][1024], 0-pad.
__global__ __launch_bounds__(256) void k_xgather(const bf16* __restrict__ xb,
                                                 bf16* __restrict__ xc) {
  int idx = blockIdx.x * 256 + threadIdx.x;   // 1408 blocks: 2816 rows x 128 gr
  int row = idx >> 7, gr = idx & 127;
  int b = row / 1408, ci = row % 1408;
  int s = ci2s_full(ci);
  bf16x8 v = {};
  if (s < 2048) v = *(const bf16x8*)&xb[(size_t)(b * 2048 + s) * 1024 + gr * 8];
  *(bf16x8*)&xc[(size_t)row * 1024 + gr * 8] = v;
}

// V-half of kvc -> Vc[bh][64][1408]; u32-packed LDS transpose (pure, no gather).
__global__ __launch_bounds__(256) void k_vtrans(const bf16* __restrict__ kvc,
                                                bf16* __restrict__ vc) {
  __shared__ unsigned L[32 * 65];
  int blk = blockIdx.x;                 // 32 bh * 22 cichunks = 704
  int bh = blk / 22, cc = blk % 22;
  int b = bh >> 4, h = bh & 15;
  int ci0 = cc * 64;
  int tid = threadIdx.x;
  int p = tid >> 3, d0 = (tid & 7) * 8;
  const bf16* src = kvc + (size_t)(b * 1408 + ci0 + 2 * p) * 2048 + 1024 + h * 64 + d0;
  u16x8 e  = *(const u16x8*)src;
  u16x8 od = *(const u16x8*)(src + 2048);
#pragma unroll
  for (int k2 = 0; k2 < 8; ++k2)
    L[p * 65 + d0 + k2] = (unsigned)e[k2] | ((unsigned)od[k2] << 16);
  __syncthreads();
#pragma unroll
  for (int it = 0; it < 2; ++it) {
    int d = it * 32 + (tid >> 3), jg = tid & 7;
    unsigned q4[4];
#pragma unroll
    for (int jj = 0; jj < 4; ++jj) q4[jj] = L[(jg * 4 + jj) * 65 + d];
    *(uint4*)&vc[((size_t)bh * 64 + d) * 1408 + ci0 + jg * 8] = *(uint4*)q4;
  }
}

// ---------------- 128^2 dbuf GEMM: C[M,N] = A[M,K] @ Bt[N,K]^T + bias ------
// granule XOR-swizzle + 2-phase prefetch (R8-proven).
template <typename OutT>
__global__ __launch_bounds__(256) void k_gemm_bt(const bf16* __restrict__ A,
                                                 const bf16* __restrict__ Bt,
                                                 const float* __restrict__ bias,
                                                 OutT* __restrict__ C,
                                                 int K, int N) {
  __shared__ bf16 As[2][128 * 32];
  __shared__ bf16 Bs[2][128 * 32];
  const int tid = threadIdx.x;
  const int w = tid >> 6, l = tid & 63, g = l >> 4, c = l & 15;
  const int wr = w >> 1, wc = w & 1;
  int lin = blockIdx.y * gridDim.x + blockIdx.x;
  int chunk = (gridDim.x * gridDim.y) >> 3;
  int nl = (lin & 7) * chunk + (lin >> 3);
  const int row0 = (nl % gridDim.x) * 128, col0 = (nl / gridDim.x) * 128;
  f32x4 acc[4][4] = {};

  auto stage = [&](int buf, int k0) {
#pragma unroll
    for (int it = 0; it < 2; ++it) {
      int idx = it * 256 + tid;
      int r = idx >> 2, cc = idx & 3;
      int jj = cc ^ ((r >> 1) & 3);
      gload16(A  + (size_t)(row0 + r) * K + k0 + jj * 8, &As[buf][idx * 8]);
      gload16(Bt + (size_t)(col0 + r) * K + k0 + jj * 8, &Bs[buf][idx * 8]);
    }
  };

  stage(0, 0);
  int cur = 0;
#pragma unroll 1
  for (int k0 = 0; k0 < K; k0 += 32) {
    asm volatile("s_waitcnt vmcnt(0)" ::: "memory");
    __builtin_amdgcn_sched_barrier(0);
    __builtin_amdgcn_s_barrier();
    __builtin_amdgcn_sched_barrier(0);

    if (k0 + 32 < K) stage(cur ^ 1, k0 + 32);

    bf16x8 af[4], bfr[4];
#pragma unroll
    for (int m = 0; m < 4; ++m) {
      int row = wr * 64 + m * 16 + c;
      af[m] = *(const bf16x8*)&As[cur][row * 32 + (g ^ ((row >> 1) & 3)) * 8];
    }
#pragma unroll
    for (int n = 0; n < 4; ++n) {
      int row = wc * 64 + n * 16 + c;
      bfr[n] = *(const bf16x8*)&Bs[cur][row * 32 + (g ^ ((row >> 1) & 3)) * 8];
    }
#pragma unroll
    for (int m = 0; m < 4; ++m)
#pragma unroll
      for (int n = 0; n < 4; ++n)
        acc[m][n] = __builtin_amdgcn_mfma_f32_16x16x32_bf16(af[m], bfr[n],
                                                            acc[m][n], 0, 0, 0);
    cur ^= 1;
  }

#pragma unroll
  for (int m = 0; m < 4; ++m) {
    int row = row0 + wr * 64 + m * 16 + g * 4;
#pragma unroll
    for (int n = 0; n < 4; ++n) {
      int col = col0 + wc * 64 + n * 16 + c;
      float bv = bias[col];
#pragma unroll
      for (int r = 0; r < 4; ++r) {
        float v = acc[m][n][r] + bv;
        C[(size_t)(row + r) * N + col] = (OutT)v;
      }
    }
  }
}

// ---------------- flash attention v8: compact K direct from KV GEMM -------
// K rows come from kvc[2816][2048] (K half, stride 2048); V from vcb.
// Pad rows (ci>=1366) map to s>=2048 -> always causal-masked; V pads get P=0.
__global__ __launch_bounds__(256, 4) void k_attn(const bf16* __restrict__ qbuf,
                                                 const bf16* __restrict__ kvc,
                                                 const bf16* __restrict__ vc,
                                                 bf16* __restrict__ att) {
  const int idx = blockIdx.x;
  const int slot = idx >> 8, j = idx & 255;
  const int r8 = j >> 5, bh = j & 31;
  const int b = bh >> 4, h = bh & 15;
  int qt;
  switch (slot) {
    case 0: qt = r8;       break;
    case 1: qt = 31 - r8;  break;
    case 2: qt = r8 + 8;   break;
    default: qt = 23 - r8; break;
  }

  const int tid = threadIdx.x;
  const int w = tid >> 6, l = tid & 63, g = l >> 4, c = l & 15;
  const int qw0 = qt * 64 + w * 16;
  const int qq = qw0 + c;

  const int nt = (keptcnt(qt * 64 + 64) + 63) >> 6;
  const int tmaskw = keptcnt(qw0 + 1) >> 6;

  __shared__ bf16 Ks[2][64 * 64];
  __shared__ bf16 Vs[2][64 * 64];
  __shared__ bf16 Plds[4][16 * 64];

  const bf16* kgc = kvc + (size_t)b * 1408 * 2048 + h * 64;
  const bf16* vgc = vc + (size_t)bh * 64 * 1408;

  auto stage = [&](int buf, int t) {
    int s0 = t * 64;
#pragma unroll
    for (int it = 0; it < 2; ++it) {
      int ch = it * 256 + tid;
      int rr = ch >> 3, jj = (ch & 7) ^ (rr & 7);
      gload16(kgc + (size_t)(s0 + rr) * 2048 + jj * 8, &Ks[buf][ch * 8]);
      gload16(vgc + (size_t)rr * 1408 + s0 + jj * 8, &Vs[buf][ch * 8]);
    }
  };

  const bf16* qb = qbuf + (size_t)(b * 2048 + qq) * 1024 + h * 64 + g * 8;
  bf16x8 qf0 = *(const bf16x8*)qb;
  bf16x8 qf1 = *(const bf16x8*)(qb + 32);
#pragma unroll
  for (int jq = 0; jq < 8; ++jq) {
    qf0[jq] = (bf16)((float)qf0[jq] * 0.125f);
    qf1[jq] = (bf16)((float)qf1[jq] * 0.125f);
  }

  f32x4 o[4] = {};
  float mrow = -1e30f, ell = 0.f;

  stage(0, 0);

  int cur = 0;
#pragma unroll 1
  for (int t = 0; t < nt; ++t) {
    asm volatile("s_waitcnt vmcnt(0)" ::: "memory");
    __builtin_amdgcn_sched_barrier(0);
    __builtin_amdgcn_s_barrier();
    __builtin_amdgcn_sched_barrier(0);

    if (t + 1 < nt) stage(cur ^ 1, t + 1);

    f32x4 ss[4] = {};
#pragma unroll
    for (int st = 0; st < 4; ++st) {
      bf16x8 ka  = *(const bf16x8*)swz(&Ks[cur][0], st * 16 + c, g * 16);
      bf16x8 kb2 = *(const bf16x8*)swz(&Ks[cur][0], st * 16 + c, 64 + g * 16);
      ss[st] = __builtin_amdgcn_mfma_f32_16x16x32_bf16(ka,  qf0, ss[st], 0, 0, 0);
      ss[st] = __builtin_amdgcn_mfma_f32_16x16x32_bf16(kb2, qf1, ss[st], 0, 0, 0);
    }

    float mloc = -1e30f;
    if (t >= tmaskw) {
#pragma unroll
      for (int st = 0; st < 4; ++st)
#pragma unroll
        for (int r = 0; r < 4; ++r) {
          int ci = t * 64 + st * 16 + g * 4 + r;
          int s = ci2s(ci);
          if (t == 0) s = (ci < 2) ? ci : s;
          float v = (s <= qq) ? ss[st][r] : -1e30f;
          ss[st][r] = v;
          mloc = fmaxf(mloc, v);
        }
    } else {
#pragma unroll
      for (int st = 0; st < 4; ++st)
#pragma unroll
        for (int r = 0; r < 4; ++r) mloc = fmaxf(mloc, ss[st][r]);
    }
    mloc = fmaxf(mloc, __shfl_xor(mloc, 16));
    mloc = fmaxf(mloc, __shfl_xor(mloc, 32));

    float mn = fmaxf(mrow, mloc);
    float al = __expf(mrow - mn);
    mrow = mn;
    float rsum = 0.f;
#pragma unroll
    for (int st = 0; st < 4; ++st) {
      float p0 = __expf(ss[st][0] - mn);
      float p1 = __expf(ss[st][1] - mn);
      float p2 = __expf(ss[st][2] - mn);
      float p3 = __expf(ss[st][3] - mn);
      rsum += (p0 + p1) + (p2 + p3);
      bf16x4 pk = {(bf16)p0, (bf16)p1, (bf16)p2, (bf16)p3};
      *(bf16x4*)swz(&Plds[w][0], c, st * 32 + g * 8) = pk;
    }
    rsum += __shfl_xor(rsum, 16);
    rsum += __shfl_xor(rsum, 32);
    ell = ell * al + rsum;
#pragma unroll
    for (int dc = 0; dc < 4; ++dc)
#pragma unroll
      for (int r = 0; r < 4; ++r) o[dc][r] *= al;

    asm volatile("s_waitcnt lgkmcnt(0)" ::: "memory");
    __builtin_amdgcn_sched_barrier(0);

#pragma unroll
    for (int kk = 0; kk < 2; ++kk) {
      bf16x8 pf = *(const bf16x8*)swz(&Plds[w][0], c, kk * 64 + g * 16);
#pragma unroll
      for (int dc = 0; dc < 4; ++dc) {
        bf16x8 vf = *(const bf16x8*)swz(&Vs[cur][0], dc * 16 + c, kk * 64 + g * 16);
        o[dc] = __builtin_amdgcn_mfma_f32_16x16x32_bf16(vf, pf, o[dc], 0, 0, 0);
      }
    }

    cur ^= 1;
  }

  float inv = 1.f / ell;
#pragma unroll
  for (int dc = 0; dc < 4; ++dc) {
    bf16x4 ok4 = {(bf16)(o[dc][0] * inv), (bf16)(o[dc][1] * inv),
                  (bf16)(o[dc][2] * inv), (bf16)(o[dc][3] * inv)};
    *(bf16x4*)swz(&Plds[w][0], c, dc * 32 + g * 8) = ok4;
  }
  asm volatile("s_waitcnt lgkmcnt(0)" ::: "memory");
  __builtin_amdgcn_sched_barrier(0);
#pragma unroll
  for (int p = 0; p < 2; ++p) {
    int row = p * 8 + (l >> 3);
    bf16x8 vrow = *(const bf16x8*)swz(&Plds[w][0], row, (l & 7) * 16);
    *(bf16x8*)&att[(size_t)(b * 2048 + qt * 64 + w * 16 + row) * 1024 +
                   h * 64 + (l & 7) * 8] = vrow;
  }
}

// ---------------- launcher ----------------
extern "C" void kernel_launch(void* const* d_in, const int* in_sizes, int n_in,
                              void* d_out, int out_size, void* d_ws, size_t ws_size,
                              hipStream_t stream) {
  const float* x  = (const float*)d_in[0];
  const float* Wq = (const float*)d_in[1];
  const float* bq = (const float*)d_in[2];
  const float* Wk = (const float*)d_in[3];
  const float* bk = (const float*)d_in[4];
  const float* Wv = (const float*)d_in[5];
  const float* bv = (const float*)d_in[6];
  const float* Wp = (const float*)d_in[7];
  const float* bp = (const float*)d_in[8];
  float* out = (float*)d_out;

  char* ws = (char*)d_ws;
  const size_t MB = 1024 * 1024;
  bf16*  xb    = (bf16*)(ws);             // 8 MB [4096][1024]; reused as att
  bf16*  wqkvT = (bf16*)(ws + 8 * MB);    // 6 MB [3072][1024]
  bf16*  wpT   = (bf16*)(ws + 14 * MB);   // 2 MB [1024][1024]
  float* bcat  = (float*)(ws + 16 * MB);  // 12 KB
  bf16*  qbuf  = (bf16*)(ws + 17 * MB);   // 8 MB [4096][1024]
  bf16*  kvc   = (bf16*)(ws + 25 * MB);   // 11 MB [2816][2048] (K|V compact)
  bf16*  vcb   = (bf16*)(ws + 36 * MB);   // 5.5 MB [32][64][1408]
  bf16*  xcb   = (bf16*)(ws + 42 * MB);   // 5.5 MB [2816][1024]
  bf16*  att   = xb;                      // alias: xb dead after KV GEMM

  k_cvt_bf16<<<2048, 256, 0, stream>>>(x, xb, 524288);
  k_wt_all<<<2060, 256, 0, stream>>>(Wq, Wk, Wv, Wp, bq, bk, bv, wqkvT, wpT, bcat);
  k_xgather<<<1408, 256, 0, stream>>>(xb, xcb);

  // Q: [4096,1024] = xb @ WqT
  k_gemm_bt<bf16><<<dim3(32, 8), 256, 0, stream>>>(xb, wqkvT, bcat, qbuf, 1024, 1024);
  // KV (compact rows): [2816,2048] = xcb @ [Wk|Wv]T
  k_gemm_bt<bf16><<<dim3(22, 16), 256, 0, stream>>>(xcb, wqkvT + 1024 * 1024,
                                                    bcat + 1024, kvc, 1024, 2048);
  k_vtrans<<<704, 256, 0, stream>>>(kvc, vcb);
  k_attn<<<1024, 256, 0, stream>>>(qbuf, kvc, vcb, att);
  k_gemm_bt<float><<<dim3(32, 8), 256, 0, stream>>>(att, wpT, bp, out, 1024, 1024);
}

// Round 12
// 107.091 us; speedup vs baseline: 1.1891x; 1.1891x over previous
//
#include <hip/hip_runtime.h>

#define AS_GLOBAL __attribute__((address_space(1)))
#define AS_LDS    __attribute__((address_space(3)))

typedef __bf16 bf16;
typedef __bf16 bf16x4 __attribute__((ext_vector_type(4)));
typedef __bf16 bf16x8 __attribute__((ext_vector_type(8)));
typedef float  f32x4  __attribute__((ext_vector_type(4)));
typedef unsigned short u16x8 __attribute__((ext_vector_type(8)));

__device__ __forceinline__ void gload16(const void* g, void* l) {
  __builtin_amdgcn_global_load_lds((const AS_GLOBAL unsigned int*)g,
                                   (AS_LDS unsigned int*)l, 16, 0, 0);
}

// swizzled LDS address for a [R][128B] row-major tile:
// stored_byte = row*128 + (bytecol ^ ((row&7)<<4))
__device__ __forceinline__ void* swz(void* base, int row, int bytecol) {
  return (char*)base + row * 128 + (bytecol ^ ((row & 7) << 4));
}

// compacted-column helpers: kept columns are s with !(s%3==1 && s>=4).
__device__ __forceinline__ int keptcnt(int X) { return X - ((X - 2) < 0 ? 0 : (X - 2) / 3); }
__device__ __forceinline__ int ci2s(int ci) {
  return 3 * ((ci - 2) >> 1) + 2 + ((ci - 2) & 1);
}
__device__ __forceinline__ int ci2s_full(int ci) {
  return ci < 2 ? ci : ci2s(ci);
}

// ---------------- fused prep: x->bf16 | 4x W^T | bias concat --------------
__global__ __launch_bounds__(256) void k_prep(const float* __restrict__ x,
                                              const float* __restrict__ Wq,
                                              const float* __restrict__ Wk,
                                              const float* __restrict__ Wv,
                                              const float* __restrict__ Wp,
                                              const float* __restrict__ bq,
                                              const float* __restrict__ bk,
                                              const float* __restrict__ bv,
                                              bf16* __restrict__ xb,
                                              bf16* __restrict__ wqkvT,
                                              bf16* __restrict__ wpT,
                                              float* __restrict__ bc) {
  int blk = blockIdx.x;
  if (blk < 2048) {
    int i = blk * 256 + threadIdx.x;
    const float4* p = (const float4*)(x + (size_t)i * 8);
    float4 a = p[0], b = p[1];
    bf16x8 v;
    v[0] = (bf16)a.x; v[1] = (bf16)a.y; v[2] = (bf16)a.z; v[3] = (bf16)a.w;
    v[4] = (bf16)b.x; v[5] = (bf16)b.y; v[6] = (bf16)b.z; v[7] = (bf16)b.w;
    *(bf16x8*)(xb + (size_t)i * 8) = v;
  } else if (blk < 4096) {
    int wblk = blk - 2048;
    int sel = wblk >> 9;
    const float* W = (sel == 0) ? Wq : (sel == 1) ? Wk : (sel == 2) ? Wv : Wp;
    bf16* dst = (sel < 3) ? (wqkvT + (size_t)sel * 1024 * 1024) : wpT;
    int lin = (wblk & 511) * 256 + threadIdx.x;
    int n = lin & 1023, kc = lin >> 10;
    bf16x8 v;
#pragma unroll
    for (int j = 0; j < 8; ++j) v[j] = (bf16)W[(size_t)(kc * 8 + j) * 1024 + n];
    *(bf16x8*)&dst[(size_t)n * 1024 + kc * 8] = v;
  } else {
    int i = (blk - 4096) * 256 + threadIdx.x;   // 0..3071
    bc[i] = (i < 1024) ? bq[i] : (i < 2048 ? bk[i - 1024] : bv[i - 2048]);
  }
}

// ---------------- fused compact: K gather | V gather+transpose ------------
__global__ __launch_bounds__(256) void k_compact(const bf16* __restrict__ qkv,
                                                 bf16* __restrict__ kc,
                                                 bf16* __restrict__ vc) {
  __shared__ unsigned L[32 * 65];
  int blk = blockIdx.x;
  int tid = threadIdx.x;
  if (blk < 1408) {
    int bh = blk / 44, rc = blk % 44;
    int b = bh >> 4, h = bh & 15;
    int rr = tid >> 3, ch = tid & 7;
    int ci = rc * 32 + rr;
    int s = ci2s_full(ci);
    bf16x8 v = {};
    if (s < 2048)
      v = *(const bf16x8*)&qkv[(size_t)(b * 2048 + s) * 3072 + 1024 + h * 64 + ch * 8];
    *(bf16x8*)&kc[((size_t)bh * 1408 + ci) * 64 + ch * 8] = v;
  } else {
    int vblk = blk - 1408;                // 32 bh * 22 cichunks = 704
    int bh = vblk / 22, cc = vblk % 22;
    int b = bh >> 4, h = bh & 15;
    int ci0 = cc * 64;
    int p = tid >> 3, d0 = (tid & 7) * 8;
    int s0 = ci2s_full(ci0 + 2 * p), s1 = ci2s_full(ci0 + 2 * p + 1);
    u16x8 e = {}, od = {};
    if (s0 < 2048)
      e = *(const u16x8*)&qkv[(size_t)(b * 2048 + s0) * 3072 + 2048 + h * 64 + d0];
    if (s1 < 2048)
      od = *(const u16x8*)&qkv[(size_t)(b * 2048 + s1) * 3072 + 2048 + h * 64 + d0];
#pragma unroll
    for (int k2 = 0; k2 < 8; ++k2)
      L[p * 65 + d0 + k2] = (unsigned)e[k2] | ((unsigned)od[k2] << 16);
    __syncthreads();
#pragma unroll
    for (int it = 0; it < 2; ++it) {
      int d = it * 32 + (tid >> 3), jg = tid & 7;
      unsigned q4[4];
#pragma unroll
      for (int jj = 0; jj < 4; ++jj) q4[jj] = L[(jg * 4 + jj) * 65 + d];
      *(uint4*)&vc[((size_t)bh * 64 + d) * 1408 + ci0 + jg * 8] = *(uint4*)q4;
    }
  }
}

// ---------------- 128^2 dbuf GEMM: C[M,N] = A[M,K] @ Bt[N,K]^T + bias ------
// granule XOR-swizzle + 2-phase prefetch; __syncthreads for iron-clad sync.
template <typename OutT>
__global__ __launch_bounds__(256) void k_gemm_bt(const bf16* __restrict__ A,
                                                 const bf16* __restrict__ Bt,
                                                 const float* __restrict__ bias,
                                                 OutT* __restrict__ C,
                                                 int K, int N) {
  __shared__ bf16 As[2][128 * 32];
  __shared__ bf16 Bs[2][128 * 32];
  const int tid = threadIdx.x;
  const int w = tid >> 6, l = tid & 63, g = l >> 4, c = l & 15;
  const int wr = w >> 1, wc = w & 1;
  int lin = blockIdx.y * gridDim.x + blockIdx.x;
  int chunk = (gridDim.x * gridDim.y) >> 3;
  int nl = (lin & 7) * chunk + (lin >> 3);
  const int row0 = (nl % gridDim.x) * 128, col0 = (nl / gridDim.x) * 128;
  f32x4 acc[4][4] = {};

  auto stage = [&](int buf, int k0) {
#pragma unroll
    for (int it = 0; it < 2; ++it) {
      int idx = it * 256 + tid;
      int r = idx >> 2, cc = idx & 3;
      int jj = cc ^ ((r >> 1) & 3);
      gload16(A  + (size_t)(row0 + r) * K + k0 + jj * 8, &As[buf][idx * 8]);
      gload16(Bt + (size_t)(col0 + r) * K + k0 + jj * 8, &Bs[buf][idx * 8]);
    }
  };

  stage(0, 0);
  int cur = 0;
#pragma unroll 1
  for (int k0 = 0; k0 < K; k0 += 32) {
    __syncthreads();   // drains vmcnt (stage(k0) landed) + full memory fence

    if (k0 + 32 < K) stage(cur ^ 1, k0 + 32);

    bf16x8 af[4], bfr[4];
#pragma unroll
    for (int m = 0; m < 4; ++m) {
      int row = wr * 64 + m * 16 + c;
      af[m] = *(const bf16x8*)&As[cur][row * 32 + (g ^ ((row >> 1) & 3)) * 8];
    }
#pragma unroll
    for (int n = 0; n < 4; ++n) {
      int row = wc * 64 + n * 16 + c;
      bfr[n] = *(const bf16x8*)&Bs[cur][row * 32 + (g ^ ((row >> 1) & 3)) * 8];
    }
#pragma unroll
    for (int m = 0; m < 4; ++m)
#pragma unroll
      for (int n = 0; n < 4; ++n)
        acc[m][n] = __builtin_amdgcn_mfma_f32_16x16x32_bf16(af[m], bfr[n],
                                                            acc[m][n], 0, 0, 0);
    cur ^= 1;
  }

#pragma unroll
  for (int m = 0; m < 4; ++m) {
    int row = row0 + wr * 64 + m * 16 + g * 4;
#pragma unroll
    for (int n = 0; n < 4; ++n) {
      int col = col0 + wc * 64 + n * 16 + c;
      float bv = bias[col];
#pragma unroll
      for (int r = 0; r < 4; ++r) {
        float v = acc[m][n][r] + bv;
        C[(size_t)(row + r) * N + col] = (OutT)v;
      }
    }
  }
}

// ---------------- flash attention v7: compacted K/V -----------------------
__global__ __launch_bounds__(256, 4) void k_attn(const bf16* __restrict__ qkv,
                                                 const bf16* __restrict__ kc,
                                                 const bf16* __restrict__ vc,
                                                 bf16* __restrict__ att) {
  const int idx = blockIdx.x;
  const int slot = idx >> 8, j = idx & 255;
  const int r8 = j >> 5, bh = j & 31;
  const int b = bh >> 4, h = bh & 15;
  int qt;
  switch (slot) {
    case 0: qt = r8;       break;
    case 1: qt = 31 - r8;  break;
    case 2: qt = r8 + 8;   break;
    default: qt = 23 - r8; break;
  }

  const int tid = threadIdx.x;
  const int w = tid >> 6, l = tid & 63, g = l >> 4, c = l & 15;
  const int qw0 = qt * 64 + w * 16;
  const int qq = qw0 + c;

  const int nt = (keptcnt(qt * 64 + 64) + 63) >> 6;
  const int tmaskw = keptcnt(qw0 + 1) >> 6;

  __shared__ bf16 Ks[2][64 * 64];
  __shared__ bf16 Vs[2][64 * 64];
  __shared__ bf16 Plds[4][16 * 64];

  const bf16* kgc = kc + (size_t)bh * 1408 * 64;
  const bf16* vgc = vc + (size_t)bh * 64 * 1408;

  auto stage = [&](int buf, int t) {
    int s0 = t * 64;
#pragma unroll
    for (int it = 0; it < 2; ++it) {
      int ch = it * 256 + tid;
      int rr = ch >> 3, jj = (ch & 7) ^ (rr & 7);
      gload16(kgc + (size_t)(s0 + rr) * 64 + jj * 8, &Ks[buf][ch * 8]);
      gload16(vgc + (size_t)rr * 1408 + s0 + jj * 8, &Vs[buf][ch * 8]);
    }
  };

  const bf16* qb = qkv + (size_t)(b * 2048 + qq) * 3072 + h * 64 + g * 8;
  bf16x8 qf0 = *(const bf16x8*)qb;
  bf16x8 qf1 = *(const bf16x8*)(qb + 32);
#pragma unroll
  for (int jq = 0; jq < 8; ++jq) {
    qf0[jq] = (bf16)((float)qf0[jq] * 0.125f);
    qf1[jq] = (bf16)((float)qf1[jq] * 0.125f);
  }

  f32x4 o[4] = {};
  float mrow = -1e30f, ell = 0.f;

  stage(0, 0);

  int cur = 0;
#pragma unroll 1
  for (int t = 0; t < nt; ++t) {
    __syncthreads();   // stage(t) landed everywhere; all waves done with t-1

    if (t + 1 < nt) stage(cur ^ 1, t + 1);

    f32x4 ss[4] = {};
#pragma unroll
    for (int st = 0; st < 4; ++st) {
      bf16x8 ka  = *(const bf16x8*)swz(&Ks[cur][0], st * 16 + c, g * 16);
      bf16x8 kb2 = *(const bf16x8*)swz(&Ks[cur][0], st * 16 + c, 64 + g * 16);
      ss[st] = __builtin_amdgcn_mfma_f32_16x16x32_bf16(ka,  qf0, ss[st], 0, 0, 0);
      ss[st] = __builtin_amdgcn_mfma_f32_16x16x32_bf16(kb2, qf1, ss[st], 0, 0, 0);
    }

    float mloc = -1e30f;
    if (t >= tmaskw) {
#pragma unroll
      for (int st = 0; st < 4; ++st)
#pragma unroll
        for (int r = 0; r < 4; ++r) {
          int ci = t * 64 + st * 16 + g * 4 + r;
          int s = ci2s(ci);
          if (t == 0) s = (ci < 2) ? ci : s;
          float v = (s <= qq) ? ss[st][r] : -1e30f;
          ss[st][r] = v;
          mloc = fmaxf(mloc, v);
        }
    } else {
#pragma unroll
      for (int st = 0; st < 4; ++st)
#pragma unroll
        for (int r = 0; r < 4; ++r) mloc = fmaxf(mloc, ss[st][r]);
    }
    mloc = fmaxf(mloc, __shfl_xor(mloc, 16));
    mloc = fmaxf(mloc, __shfl_xor(mloc, 32));

    float mn = fmaxf(mrow, mloc);
    float al = __expf(mrow - mn);
    mrow = mn;
    float rsum = 0.f;
#pragma unroll
    for (int st = 0; st < 4; ++st) {
      float p0 = __expf(ss[st][0] - mn);
      float p1 = __expf(ss[st][1] - mn);
      float p2 = __expf(ss[st][2] - mn);
      float p3 = __expf(ss[st][3] - mn);
      rsum += (p0 + p1) + (p2 + p3);
      bf16x4 pk = {(bf16)p0, (bf16)p1, (bf16)p2, (bf16)p3};
      *(bf16x4*)swz(&Plds[w][0], c, st * 32 + g * 8) = pk;
    }
    rsum += __shfl_xor(rsum, 16);
    rsum += __shfl_xor(rsum, 32);
    ell = ell * al + rsum;
#pragma unroll
    for (int dc = 0; dc < 4; ++dc)
#pragma unroll
      for (int r = 0; r < 4; ++r) o[dc][r] *= al;

    // wave-private P cross-lane round trip (rule #18 fence pair)
    asm volatile("s_waitcnt lgkmcnt(0)" ::: "memory");
    __builtin_amdgcn_sched_barrier(0);

#pragma unroll
    for (int kk = 0; kk < 2; ++kk) {
      bf16x8 pf = *(const bf16x8*)swz(&Plds[w][0], c, kk * 64 + g * 16);
#pragma unroll
      for (int dc = 0; dc < 4; ++dc) {
        bf16x8 vf = *(const bf16x8*)swz(&Vs[cur][0], dc * 16 + c, kk * 64 + g * 16);
        o[dc] = __builtin_amdgcn_mfma_f32_16x16x32_bf16(vf, pf, o[dc], 0, 0, 0);
      }
    }

    cur ^= 1;
  }

  float inv = 1.f / ell;
#pragma unroll
  for (int dc = 0; dc < 4; ++dc) {
    bf16x4 ok4 = {(bf16)(o[dc][0] * inv), (bf16)(o[dc][1] * inv),
                  (bf16)(o[dc][2] * inv), (bf16)(o[dc][3] * inv)};
    *(bf16x4*)swz(&Plds[w][0], c, dc * 32 + g * 8) = ok4;
  }
  asm volatile("s_waitcnt lgkmcnt(0)" ::: "memory");
  __builtin_amdgcn_sched_barrier(0);
#pragma unroll
  for (int p = 0; p < 2; ++p) {
    int row = p * 8 + (l >> 3);
    bf16x8 vrow = *(const bf16x8*)swz(&Plds[w][0], row, (l & 7) * 16);
    *(bf16x8*)&att[(size_t)(b * 2048 + qt * 64 + w * 16 + row) * 1024 +
                   h * 64 + (l & 7) * 8] = vrow;
  }
}

// ---------------- launcher ----------------
extern "C" void kernel_launch(void* const* d_in, const int* in_sizes, int n_in,
                              void* d_out, int out_size, void* d_ws, size_t ws_size,
                              hipStream_t stream) {
  const float* x  = (const float*)d_in[0];
  const float* Wq = (const float*)d_in[1];
  const float* bq = (const float*)d_in[2];
  const float* Wk = (const float*)d_in[3];
  const float* bk = (const float*)d_in[4];
  const float* Wv = (const float*)d_in[5];
  const float* bv = (const float*)d_in[6];
  const float* Wp = (const float*)d_in[7];
  const float* bp = (const float*)d_in[8];
  float* out = (float*)d_out;

  char* ws = (char*)d_ws;
  const size_t MB = 1024 * 1024;
  bf16*  xb    = (bf16*)(ws);             // 8 MB [4096][1024]; reused as att
  bf16*  wqkvT = (bf16*)(ws + 8 * MB);    // 6 MB [3072][1024]
  bf16*  wpT   = (bf16*)(ws + 14 * MB);   // 2 MB [1024][1024]
  float* bcat  = (float*)(ws + 16 * MB);  // 12 KB
  bf16*  qkv   = (bf16*)(ws + 17 * MB);   // 24 MB [4096][3072]
  bf16*  vcb   = (bf16*)(ws + 41 * MB);   // 5.5 MB [32][64][1408]
  bf16*  kcb   = (bf16*)(ws + 47 * MB);   // 5.5 MB [32][1408][64] (no aliasing)
  bf16*  att   = xb;                      // alias: xb dead after QKV GEMM

  // 1: all preps (cvt + 4x W^T + bias concat)
  k_prep<<<4108, 256, 0, stream>>>(x, Wq, Wk, Wv, Wp, bq, bk, bv,
                                   xb, wqkvT, wpT, bcat);
  // 2: QKV GEMM [4096,1024]x[1024,3072]
  k_gemm_bt<bf16><<<dim3(32, 24), 256, 0, stream>>>(xb, wqkvT, bcat, qkv, 1024, 3072);
  // 3: K gather + V gather/transpose
  k_compact<<<2112, 256, 0, stream>>>(qkv, kcb, vcb);
  // 4: attention
  k_attn<<<1024, 256, 0, stream>>>(qkv, kcb, vcb, att);
  // 5: output projection
  k_gemm_bt<float><<<dim3(32, 8), 256, 0, stream>>>(att, wpT, bp, out, 1024, 1024);
}